// Round 15
// baseline (124.264 us; speedup 1.0000x reference)
//
#include <hip/hip_runtime.h>
#include <hip/hip_bf16.h>
#include <math.h>

#define D_IN   256
#define HD     128
#define NHEAD  4
#define NEG_SLOPE 0.2f
#define CHUNK 32
#define MAXB  1024      // max dst-buckets (N <= 65536)
#define BCAP  2560      // padded edges per 64-dst bucket (mean 2048, +11 sigma)

typedef _Float16 h8 __attribute__((ext_vector_type(8)));
typedef _Float16 h4 __attribute__((ext_vector_type(4)));
typedef _Float16 h2 __attribute__((ext_vector_type(2)));
typedef float f4 __attribute__((ext_vector_type(4)));

#define SWZ(row, byte) ((byte) ^ (((row) & 7) << 4))

// ---------------- W f32 -> f16 (once) + zero gcur; 33 blocks ----------------
__global__ __launch_bounds__(256) void wconv_k(const float* __restrict__ fcw,
                                               unsigned short* __restrict__ wf16,
                                               int* __restrict__ gcur, int B) {
    const int t = threadIdx.x;
    if (blockIdx.x < 32) {
        int i = blockIdx.x * 256 + t;
        float4 v = *(const float4*)&fcw[i * 4];
        h4 p = {(_Float16)v.x, (_Float16)v.y, (_Float16)v.z, (_Float16)v.w};
        *(h4*)&wf16[i * 4] = p;
        return;
    }
    for (int i = t; i < B; i += 256) gcur[i] = 0;
}

// ---------------- fused: gemm blocks [0,GB) + bin blocks [GB,GB+ebl) ----------------
// Register-lean on both bodies; launch_bounds forces >=6 waves/SIMD residency.
__global__ __launch_bounds__(256, 6) void fused_k(
        const float* __restrict__ feat, const unsigned short* __restrict__ wf16,
        const float* __restrict__ attn_l, const float* __restrict__ attn_r,
        unsigned int* __restrict__ hbuf, float* __restrict__ el, float* __restrict__ er,
        const int* __restrict__ src, const int* __restrict__ dst,
        int* __restrict__ gcur, unsigned int* __restrict__ pairs,
        int N, int E, int B, int GB) {
    __shared__ __align__(16) unsigned char smem[32 * 512];   // 16 KB (union)
    const int t = threadIdx.x;

    if ((int)blockIdx.x >= GB) {
        // ================= bin body: key = dst bucket (no reg arrays) =================
        int* lcnt  = (int*)smem;          // 4 KB
        int* lbase = lcnt + MAXB;         // 4 KB
        for (int i = t; i < B; i += 256) lcnt[i] = 0;
        __syncthreads();
        const int base = ((int)blockIdx.x - GB) * 4096;
        #pragma unroll 4
        for (int k = 0; k < 16; ++k) {
            int idx = base + k * 256 + t;
            if (idx < E) atomicAdd(&lcnt[dst[idx] >> 6], 1);
        }
        __syncthreads();
        for (int i = t; i < B; i += 256) {
            int c = lcnt[i];
            lbase[i] = c ? atomicAdd(&gcur[i], c) : 0;
            lcnt[i] = 0;
        }
        __syncthreads();
        #pragma unroll 4
        for (int k = 0; k < 16; ++k) {
            int idx = base + k * 256 + t;
            if (idx < E) {
                int s = src[idx], dd = dst[idx];   // L1/L2-warm re-read
                int b = dd >> 6;
                int r = lbase[b] + atomicAdd(&lcnt[b], 1);
                if (r < BCAP)
                    pairs[(size_t)b * BCAP + r] =
                        ((unsigned int)s << 6) | (unsigned int)(dd & 63);
            }
        }
        return;
    }

    // ================= gemm body: 32 nodes x 128 out, K=256, in-loop W loads =================
    unsigned char* lds_raw = smem;
    const int l  = t & 63;
    const int w  = t >> 6;          // wave index == head
    const int l4 = l >> 4;          // k-group 0..3
    const int lm = l & 15;
    const int n0 = blockIdx.x * 32;

    // stage feat tile [32][256] -> f16 LDS, swizzled (8 float4 per thread)
    #pragma unroll
    for (int i = 0; i < 8; ++i) {
        int idx = t + 256 * i;
        int row = idx >> 6, c4 = idx & 63;
        float4 v = make_float4(0.f, 0.f, 0.f, 0.f);
        if (n0 + row < N) v = *(const float4*)&feat[(size_t)(n0 + row) * D_IN + c4 * 4];
        h4 p = {(_Float16)v.x, (_Float16)v.y, (_Float16)v.z, (_Float16)v.w};
        *(h4*)(lds_raw + row * 512 + SWZ(row, c4 * 8)) = p;
    }
    __syncthreads();

    const unsigned short* w0 = wf16 + (size_t)(w * 32 + lm) * D_IN;
    const unsigned short* w1 = wf16 + (size_t)(w * 32 + 16 + lm) * D_IN;

    f4 acc[2][2] = {};
    #pragma unroll 2
    for (int ks = 0; ks < 8; ++ks) {
        const int ko = ks * 32 + l4 * 8;
        h8 b0 = *(const h8*)&w0[ko];           // L2-hit, hidden by MFMAs
        h8 b1 = *(const h8*)&w1[ko];
        h8 af0 = *(const h8*)(lds_raw + lm * 512 + SWZ(lm, ko * 2));
        h8 af1 = *(const h8*)(lds_raw + (16 + lm) * 512 + SWZ(16 + lm, ko * 2));
        acc[0][0] = __builtin_amdgcn_mfma_f32_16x16x32_f16(af0, b0, acc[0][0], 0, 0, 0);
        acc[0][1] = __builtin_amdgcn_mfma_f32_16x16x32_f16(af0, b1, acc[0][1], 0, 0, 0);
        acc[1][0] = __builtin_amdgcn_mfma_f32_16x16x32_f16(af1, b0, acc[1][0], 0, 0, 0);
        acc[1][1] = __builtin_amdgcn_mfma_f32_16x16x32_f16(af1, b1, acc[1][1], 0, 0, 0);
    }

    float al[2], ar[2];
    #pragma unroll
    for (int jt = 0; jt < 2; ++jt) {
        al[jt] = attn_l[w * 32 + jt * 16 + lm];
        ar[jt] = attn_r[w * 32 + jt * 16 + lm];
    }
    #pragma unroll
    for (int mt = 0; mt < 2; ++mt) {
        #pragma unroll
        for (int r = 0; r < 4; ++r) {
            float vl = acc[mt][0][r] * al[0] + acc[mt][1][r] * al[1];
            float vr = acc[mt][0][r] * ar[0] + acc[mt][1][r] * ar[1];
            #pragma unroll
            for (int o = 1; o < 16; o <<= 1) {
                vl += __shfl_xor(vl, o);
                vr += __shfl_xor(vr, o);
            }
            int node = n0 + mt * 16 + l4 * 4 + r;
            if (lm == 0 && node < N) {
                el[node * NHEAD + w] = vl;
                er[node * NHEAD + w] = vr;
            }
        }
    }

    // h -> LDS f16 [32][128] -> coalesced dump
    __syncthreads();
    unsigned short* hl = (unsigned short*)lds_raw;
    #pragma unroll
    for (int mt = 0; mt < 2; ++mt)
        #pragma unroll
        for (int jt = 0; jt < 2; ++jt)
            #pragma unroll
            for (int r = 0; r < 4; ++r) {
                int node_local = mt * 16 + l4 * 4 + r;
                int ch = w * 32 + jt * 16 + lm;
                _Float16 hf = (_Float16)acc[mt][jt][r];
                hl[node_local * 128 + ch] = __builtin_bit_cast(unsigned short, hf);
            }
    __syncthreads();
    const unsigned int* hu = (const unsigned int*)lds_raw;
    #pragma unroll
    for (int i = 0; i < 8; ++i) {
        int idx = t + 256 * i;
        int row = idx >> 6, c = idx & 63;
        if (n0 + row < N) hbuf[(size_t)(n0 + row) * 64 + c] = hu[row * 64 + c];
    }
}

// ---------------- per-bucket: sort into per-dst groups, emit row_start/deg ----------------
__global__ __launch_bounds__(256) void bucket_k(const unsigned int* __restrict__ pairs,
                                                const int* __restrict__ gcur,
                                                int* __restrict__ row_start,
                                                int* __restrict__ degs,
                                                int* __restrict__ srcs, int N) {
    __shared__ int cnt64[64];
    __shared__ int base64[64];
    const int b = blockIdx.x;
    const int t = threadIdx.x;
    const int lo = b * BCAP;
    const int len = min(gcur[b], BCAP);
    if (t < 64) cnt64[t] = 0;
    __syncthreads();
    for (int i = t; i < len; i += 256)
        atomicAdd(&cnt64[pairs[lo + i] & 63], 1);
    __syncthreads();
    if (t < 64) {
        int v = cnt64[t];
        int x = v;
        #pragma unroll
        for (int o = 1; o < 64; o <<= 1) {
            int y = __shfl_up(x, o);
            if (t >= o) x += y;
        }
        int excl = lo + x - v;
        base64[t] = excl;
        int d = b * 64 + t;
        if (d < N) { row_start[d] = excl; degs[d] = v; }
        cnt64[t] = 0;
    }
    __syncthreads();
    for (int i = lo + t; i < lo + len; i += 256) {
        unsigned int p = pairs[i];
        int ld = p & 63;
        int r = atomicAdd(&cnt64[ld], 1);
        srcs[base64[ld] + r] = (int)(p >> 6);
    }
}

// ---------------- aggregate: one wave per dst, batched dwordx2 gather (r6/r12 proven) ----------------
__global__ __launch_bounds__(64) void agg_k(
        const int* __restrict__ row_start, const int* __restrict__ degs,
        const int* __restrict__ srcs,
        const float* __restrict__ el, const float* __restrict__ er,
        const unsigned int* __restrict__ hbuf, const float* __restrict__ bias,
        float* __restrict__ out, int N) {
    __shared__ float exw[CHUNK * NHEAD];
    __shared__ int s_lds[CHUNK];
    const int d = blockIdx.x;
    const int l = threadIdx.x;
    const int he = l >> 4, es = l & 15;     // C1 roles: (head, edge-slot)
    const int half = l >> 5, cl = l & 31;   // C2 roles: (edge-half, channel-quad)
    const int hc = cl >> 3;                 // head of this lane's channels
    const int base = row_start[d];
    const int deg  = degs[d];
    const float erd = er[d * NHEAD + he];

    f4 acc = {0.f, 0.f, 0.f, 0.f};
    float den = 0.f;

    for (int c0 = 0; c0 < deg; c0 += CHUNK) {
        const int clen = min(CHUNK, deg - c0);
        __syncthreads();
        // C1: pre-issue both srcs loads, then both el loads, then exp
        int s0 = -1, s1 = -1;
        if (es < clen)      s0 = srcs[base + c0 + es];
        if (es + 16 < clen) s1 = srcs[base + c0 + es + 16];
        float e0 = 0.f, e1 = 0.f;
        if (s0 >= 0) e0 = el[s0 * NHEAD + he];
        if (s1 >= 0) e1 = el[s1 * NHEAD + he];
        if (s0 >= 0) {
            float v = e0 + erd;
            v = v > 0.f ? v : NEG_SLOPE * v;
            float ex = __expf(v);
            if (he == 0) s_lds[es] = s0;
            exw[es * NHEAD + he] = ex;
            den += ex;
        }
        if (s1 >= 0) {
            float v = e1 + erd;
            v = v > 0.f ? v : NEG_SLOPE * v;
            float ex = __expf(v);
            if (he == 0) s_lds[es + 16] = s1;
            exw[(es + 16) * NHEAD + he] = ex;
            den += ex;
        }
        __syncthreads();
        // C2: 8 edges per batch (4 pair-steps), loads issued before accumulation
        for (int jj = 0; jj < clen; jj += 8) {
            uint2 hv[4];
            float ex4[4];
            int e2v[4];
            #pragma unroll
            for (int k = 0; k < 4; ++k) {
                int e2 = jj + 2 * k + half;
                e2v[k] = (e2 < clen) ? e2 : -1;
                if (e2v[k] >= 0) {
                    int s = s_lds[e2];
                    hv[k] = *(const uint2*)&hbuf[(size_t)s * 64 + cl * 2];
                    ex4[k] = exw[e2 * NHEAD + hc];
                }
            }
            #pragma unroll
            for (int k = 0; k < 4; ++k) {
                if (e2v[k] >= 0) {
                    h2 p0 = __builtin_bit_cast(h2, hv[k].x);
                    h2 p1 = __builtin_bit_cast(h2, hv[k].y);
                    acc[0] += (float)p0[0] * ex4[k];
                    acc[1] += (float)p0[1] * ex4[k];
                    acc[2] += (float)p1[0] * ex4[k];
                    acc[3] += (float)p1[1] * ex4[k];
                }
            }
        }
    }

    // combine the two half-waves (same channels, alternating edges)
    #pragma unroll
    for (int k = 0; k < 4; ++k) acc[k] += __shfl_xor(acc[k], 32);
    // reduce den over the 16 lanes of each head group
    #pragma unroll
    for (int o = 1; o < 16; o <<= 1) den += __shfl_xor(den, o);
    float denc = __shfl(den, hc << 4);
    float r = 1.0f / fmaxf(denc, 1e-9f);

    if (half == 0) {
        float4 b4 = *(const float4*)&bias[cl * 4];
        float4 o4 = make_float4(acc[0] * r + b4.x, acc[1] * r + b4.y,
                                acc[2] * r + b4.z, acc[3] * r + b4.w);
        *(float4*)&out[(size_t)d * HD + cl * 4] = o4;
    }
}

extern "C" void kernel_launch(void* const* d_in, const int* in_sizes, int n_in,
                              void* d_out, int out_size, void* d_ws, size_t ws_size,
                              hipStream_t stream) {
    const float* feat   = (const float*)d_in[0];
    const float* fcw    = (const float*)d_in[1];
    const float* attn_l = (const float*)d_in[2];
    const float* attn_r = (const float*)d_in[3];
    const float* bias   = (const float*)d_in[4];
    const int*   src    = (const int*)d_in[5];
    const int*   dst    = (const int*)d_in[6];
    float* out = (float*)d_out;

    const int N = in_sizes[0] / D_IN;
    const int E = in_sizes[5];
    const int B = (N + 63) >> 6;    // dst-buckets of 64 nodes

    unsigned int* hbuf = (unsigned int*)d_ws;                       // N*64 u32 (f16 pairs)
    float* el        = (float*)(hbuf + (size_t)N * 64);             // N*4
    float* er        = el + (size_t)N * NHEAD;                      // N*4
    unsigned short* wf16 = (unsigned short*)(er + (size_t)N * NHEAD);  // 128*256 f16
    unsigned int* pairs = (unsigned int*)(wf16 + HD * D_IN);        // B*BCAP
    int*   srcs      = (int*)(pairs + (size_t)B * BCAP);            // B*BCAP
    int*   row_start = srcs + (size_t)B * BCAP;                     // N
    int*   degs      = row_start + N;                               // N
    int*   gcur      = degs + N;                                    // B

    const int GB  = (N + 31) / 32;       // gemm blocks (32-node tiles)
    const int ebl = (E + 4095) / 4096;   // bin blocks

    wconv_k<<<33, 256, 0, stream>>>(fcw, wf16, gcur, B);
    fused_k<<<GB + ebl, 256, 0, stream>>>(feat, wf16, attn_l, attn_r, hbuf, el, er,
                                          src, dst, gcur, pairs, N, E, B, GB);
    bucket_k<<<B, 256, 0, stream>>>(pairs, gcur, row_start, degs, srcs, N);
    agg_k<<<N, 64, 0, stream>>>(row_start, degs, srcs, el, er, hbuf, bias, out, N);
}

// Round 16
// 117.567 us; speedup vs baseline: 1.0570x; 1.0570x over previous
//
#include <hip/hip_runtime.h>
#include <hip/hip_bf16.h>
#include <math.h>

#define D_IN   256
#define HD     128
#define NHEAD  4
#define NEG_SLOPE 0.2f
#define CHUNK 32
#define MAXB  1024      // max dst-buckets (N <= 65536)
#define BCAP  2560      // padded edges per 64-dst bucket (mean 2048, +11 sigma)

typedef _Float16 h8 __attribute__((ext_vector_type(8)));
typedef _Float16 h4 __attribute__((ext_vector_type(4)));
typedef _Float16 h2 __attribute__((ext_vector_type(2)));
typedef float f4 __attribute__((ext_vector_type(4)));

#define SWZ(row, byte) ((byte) ^ (((row) & 7) << 4))

// ---------------- W f32 -> f16 (once) + zero gcur; 33 blocks ----------------
__global__ __launch_bounds__(256) void wconv_k(const float* __restrict__ fcw,
                                               unsigned short* __restrict__ wf16,
                                               int* __restrict__ gcur, int B) {
    const int t = threadIdx.x;
    if (blockIdx.x < 32) {
        int i = blockIdx.x * 256 + t;
        float4 v = *(const float4*)&fcw[i * 4];
        h4 p = {(_Float16)v.x, (_Float16)v.y, (_Float16)v.z, (_Float16)v.w};
        *(h4*)&wf16[i * 4] = p;
        return;
    }
    for (int i = t; i < B; i += 256) gcur[i] = 0;
}

// ---------------- fused: gemm blocks [0,GB) + bin blocks [GB,GB+ebl) ----------------
// gemm: 32-node tile, 16 KB LDS, W-preload (r14 proven schedule).
__global__ __launch_bounds__(256) void fused_k(
        const float* __restrict__ feat, const unsigned short* __restrict__ wf16,
        const float* __restrict__ attn_l, const float* __restrict__ attn_r,
        unsigned int* __restrict__ hbuf, float* __restrict__ el, float* __restrict__ er,
        const int* __restrict__ src, const int* __restrict__ dst,
        int* __restrict__ gcur, unsigned int* __restrict__ pairs,
        int N, int E, int B, int GB) {
    __shared__ __align__(16) unsigned char smem[32 * 512];   // 16 KB (union)
    const int t = threadIdx.x;

    if ((int)blockIdx.x >= GB) {
        // ================= bin body: key = dst bucket =================
        int* lcnt  = (int*)smem;          // 4 KB
        int* lbase = lcnt + MAXB;         // 4 KB
        for (int i = t; i < B; i += 256) lcnt[i] = 0;
        __syncthreads();
        const int base = ((int)blockIdx.x - GB) * 4096;
        int sv[16], dv[16];
        #pragma unroll
        for (int k = 0; k < 16; ++k) {
            int idx = base + k * 256 + t;
            if (idx < E) {
                sv[k] = src[idx];
                dv[k] = dst[idx];
                atomicAdd(&lcnt[dv[k] >> 6], 1);
            } else dv[k] = -1;
        }
        __syncthreads();
        for (int i = t; i < B; i += 256) {
            int c = lcnt[i];
            lbase[i] = c ? atomicAdd(&gcur[i], c) : 0;
            lcnt[i] = 0;
        }
        __syncthreads();
        #pragma unroll
        for (int k = 0; k < 16; ++k) {
            if (dv[k] >= 0) {
                int b = dv[k] >> 6;
                int r = lbase[b] + atomicAdd(&lcnt[b], 1);
                if (r < BCAP)
                    pairs[(size_t)b * BCAP + r] =
                        ((unsigned int)sv[k] << 6) | (unsigned int)(dv[k] & 63);
            }
        }
        return;
    }

    // ================= gemm body: 32 nodes x 128 out, K=256 =================
    unsigned char* lds_raw = smem;
    const int l  = t & 63;
    const int w  = t >> 6;          // wave index == head
    const int l4 = l >> 4;          // k-group 0..3
    const int lm = l & 15;
    const int n0 = blockIdx.x * 32;

    // B fragments: preload (overlaps feat staging; L2-resident)
    h8 breg[2][8];
    #pragma unroll
    for (int jt = 0; jt < 2; ++jt) {
        const unsigned short* wrow = wf16 + (size_t)(w * 32 + jt * 16 + lm) * D_IN;
        #pragma unroll
        for (int ks = 0; ks < 8; ++ks)
            breg[jt][ks] = *(const h8*)&wrow[ks * 32 + l4 * 8];
    }

    // stage feat tile [32][256] -> f16 LDS, swizzled (8 float4 per thread)
    #pragma unroll
    for (int i = 0; i < 8; ++i) {
        int idx = t + 256 * i;
        int row = idx >> 6, c4 = idx & 63;
        float4 v = make_float4(0.f, 0.f, 0.f, 0.f);
        if (n0 + row < N) v = *(const float4*)&feat[(size_t)(n0 + row) * D_IN + c4 * 4];
        h4 p = {(_Float16)v.x, (_Float16)v.y, (_Float16)v.z, (_Float16)v.w};
        *(h4*)(lds_raw + row * 512 + SWZ(row, c4 * 8)) = p;
    }
    __syncthreads();

    f4 acc[2][2] = {};
    #pragma unroll
    for (int ks = 0; ks < 8; ++ks) {
        const int ko = ks * 32 + l4 * 8;
        #pragma unroll
        for (int mt = 0; mt < 2; ++mt) {
            int row = mt * 16 + lm;
            h8 af = *(const h8*)(lds_raw + row * 512 + SWZ(row, ko * 2));
            acc[mt][0] = __builtin_amdgcn_mfma_f32_16x16x32_f16(af, breg[0][ks], acc[mt][0], 0, 0, 0);
            acc[mt][1] = __builtin_amdgcn_mfma_f32_16x16x32_f16(af, breg[1][ks], acc[mt][1], 0, 0, 0);
        }
    }

    float al[2], ar[2];
    #pragma unroll
    for (int jt = 0; jt < 2; ++jt) {
        al[jt] = attn_l[w * 32 + jt * 16 + lm];
        ar[jt] = attn_r[w * 32 + jt * 16 + lm];
    }
    #pragma unroll
    for (int mt = 0; mt < 2; ++mt) {
        #pragma unroll
        for (int r = 0; r < 4; ++r) {
            float vl = acc[mt][0][r] * al[0] + acc[mt][1][r] * al[1];
            float vr = acc[mt][0][r] * ar[0] + acc[mt][1][r] * ar[1];
            #pragma unroll
            for (int o = 1; o < 16; o <<= 1) {
                vl += __shfl_xor(vl, o);
                vr += __shfl_xor(vr, o);
            }
            int node = n0 + mt * 16 + l4 * 4 + r;
            if (lm == 0 && node < N) {
                el[node * NHEAD + w] = vl;
                er[node * NHEAD + w] = vr;
            }
        }
    }

    // h -> LDS f16 [32][128] -> coalesced dump
    __syncthreads();
    unsigned short* hl = (unsigned short*)lds_raw;
    #pragma unroll
    for (int mt = 0; mt < 2; ++mt)
        #pragma unroll
        for (int jt = 0; jt < 2; ++jt)
            #pragma unroll
            for (int r = 0; r < 4; ++r) {
                int node_local = mt * 16 + l4 * 4 + r;
                int ch = w * 32 + jt * 16 + lm;
                _Float16 hf = (_Float16)acc[mt][jt][r];
                hl[node_local * 128 + ch] = __builtin_bit_cast(unsigned short, hf);
            }
    __syncthreads();
    const unsigned int* hu = (const unsigned int*)lds_raw;
    #pragma unroll
    for (int i = 0; i < 8; ++i) {
        int idx = t + 256 * i;
        int row = idx >> 6, c = idx & 63;
        if (n0 + row < N) hbuf[(size_t)(n0 + row) * 64 + c] = hu[row * 64 + c];
    }
}

// ---------------- per-bucket: sort into per-dst groups (uint4-vectorized scans) ----------------
__global__ __launch_bounds__(256) void bucket_k(const unsigned int* __restrict__ pairs,
                                                const int* __restrict__ gcur,
                                                int* __restrict__ row_start,
                                                int* __restrict__ degs,
                                                int* __restrict__ srcs, int N) {
    __shared__ int cnt64[64];
    __shared__ int base64[64];
    const int b = blockIdx.x;
    const int t = threadIdx.x;
    const int lo = b * BCAP;                 // BCAP % 4 == 0 -> 16B aligned
    const int len = min(gcur[b], BCAP);
    const int len4 = len & ~3;
    if (t < 64) cnt64[t] = 0;
    __syncthreads();
    // pass 1: histogram, 4 pairs per thread per iter
    for (int i = t * 4; i < len4; i += 1024) {
        uint4 p = *(const uint4*)&pairs[lo + i];
        atomicAdd(&cnt64[p.x & 63], 1);
        atomicAdd(&cnt64[p.y & 63], 1);
        atomicAdd(&cnt64[p.z & 63], 1);
        atomicAdd(&cnt64[p.w & 63], 1);
    }
    for (int i = len4 + t; i < len; i += 256)
        atomicAdd(&cnt64[pairs[lo + i] & 63], 1);
    __syncthreads();
    if (t < 64) {
        int v = cnt64[t];
        int x = v;
        #pragma unroll
        for (int o = 1; o < 64; o <<= 1) {
            int y = __shfl_up(x, o);
            if (t >= o) x += y;
        }
        int excl = lo + x - v;
        base64[t] = excl;
        int d = b * 64 + t;
        if (d < N) { row_start[d] = excl; degs[d] = v; }
        cnt64[t] = 0;
    }
    __syncthreads();
    // pass 2: scatter, 4 pairs per thread per iter
    for (int i = t * 4; i < len4; i += 1024) {
        uint4 p = *(const uint4*)&pairs[lo + i];
        int r0 = atomicAdd(&cnt64[p.x & 63], 1);
        srcs[base64[p.x & 63] + r0] = (int)(p.x >> 6);
        int r1 = atomicAdd(&cnt64[p.y & 63], 1);
        srcs[base64[p.y & 63] + r1] = (int)(p.y >> 6);
        int r2 = atomicAdd(&cnt64[p.z & 63], 1);
        srcs[base64[p.z & 63] + r2] = (int)(p.z >> 6);
        int r3 = atomicAdd(&cnt64[p.w & 63], 1);
        srcs[base64[p.w & 63] + r3] = (int)(p.w >> 6);
    }
    for (int i = len4 + t; i < len; i += 256) {
        unsigned int p = pairs[lo + i];
        int ld = p & 63;
        int r = atomicAdd(&cnt64[ld], 1);
        srcs[base64[ld] + r] = (int)(p >> 6);
    }
}

// ---------------- aggregate: one wave per dst, batched dwordx2 gather (r6/r12/r14 proven) ----------------
__global__ __launch_bounds__(64) void agg_k(
        const int* __restrict__ row_start, const int* __restrict__ degs,
        const int* __restrict__ srcs,
        const float* __restrict__ el, const float* __restrict__ er,
        const unsigned int* __restrict__ hbuf, const float* __restrict__ bias,
        float* __restrict__ out, int N) {
    __shared__ float exw[CHUNK * NHEAD];
    __shared__ int s_lds[CHUNK];
    const int d = blockIdx.x;
    const int l = threadIdx.x;
    const int he = l >> 4, es = l & 15;     // C1 roles: (head, edge-slot)
    const int half = l >> 5, cl = l & 31;   // C2 roles: (edge-half, channel-quad)
    const int hc = cl >> 3;                 // head of this lane's channels
    const int base = row_start[d];
    const int deg  = degs[d];
    const float erd = er[d * NHEAD + he];

    f4 acc = {0.f, 0.f, 0.f, 0.f};
    float den = 0.f;

    for (int c0 = 0; c0 < deg; c0 += CHUNK) {
        const int clen = min(CHUNK, deg - c0);
        __syncthreads();
        // C1: pre-issue both srcs loads, then both el loads, then exp
        int s0 = -1, s1 = -1;
        if (es < clen)      s0 = srcs[base + c0 + es];
        if (es + 16 < clen) s1 = srcs[base + c0 + es + 16];
        float e0 = 0.f, e1 = 0.f;
        if (s0 >= 0) e0 = el[s0 * NHEAD + he];
        if (s1 >= 0) e1 = el[s1 * NHEAD + he];
        if (s0 >= 0) {
            float v = e0 + erd;
            v = v > 0.f ? v : NEG_SLOPE * v;
            float ex = __expf(v);
            if (he == 0) s_lds[es] = s0;
            exw[es * NHEAD + he] = ex;
            den += ex;
        }
        if (s1 >= 0) {
            float v = e1 + erd;
            v = v > 0.f ? v : NEG_SLOPE * v;
            float ex = __expf(v);
            if (he == 0) s_lds[es + 16] = s1;
            exw[(es + 16) * NHEAD + he] = ex;
            den += ex;
        }
        __syncthreads();
        // C2: 8 edges per batch (4 pair-steps), loads issued before accumulation
        for (int jj = 0; jj < clen; jj += 8) {
            uint2 hv[4];
            float ex4[4];
            int e2v[4];
            #pragma unroll
            for (int k = 0; k < 4; ++k) {
                int e2 = jj + 2 * k + half;
                e2v[k] = (e2 < clen) ? e2 : -1;
                if (e2v[k] >= 0) {
                    int s = s_lds[e2];
                    hv[k] = *(const uint2*)&hbuf[(size_t)s * 64 + cl * 2];
                    ex4[k] = exw[e2 * NHEAD + hc];
                }
            }
            #pragma unroll
            for (int k = 0; k < 4; ++k) {
                if (e2v[k] >= 0) {
                    h2 p0 = __builtin_bit_cast(h2, hv[k].x);
                    h2 p1 = __builtin_bit_cast(h2, hv[k].y);
                    acc[0] += (float)p0[0] * ex4[k];
                    acc[1] += (float)p0[1] * ex4[k];
                    acc[2] += (float)p1[0] * ex4[k];
                    acc[3] += (float)p1[1] * ex4[k];
                }
            }
        }
    }

    // combine the two half-waves (same channels, alternating edges)
    #pragma unroll
    for (int k = 0; k < 4; ++k) acc[k] += __shfl_xor(acc[k], 32);
    // reduce den over the 16 lanes of each head group
    #pragma unroll
    for (int o = 1; o < 16; o <<= 1) den += __shfl_xor(den, o);
    float denc = __shfl(den, hc << 4);
    float r = 1.0f / fmaxf(denc, 1e-9f);

    if (half == 0) {
        float4 b4 = *(const float4*)&bias[cl * 4];
        float4 o4 = make_float4(acc[0] * r + b4.x, acc[1] * r + b4.y,
                                acc[2] * r + b4.z, acc[3] * r + b4.w);
        *(float4*)&out[(size_t)d * HD + cl * 4] = o4;
    }
}

extern "C" void kernel_launch(void* const* d_in, const int* in_sizes, int n_in,
                              void* d_out, int out_size, void* d_ws, size_t ws_size,
                              hipStream_t stream) {
    const float* feat   = (const float*)d_in[0];
    const float* fcw    = (const float*)d_in[1];
    const float* attn_l = (const float*)d_in[2];
    const float* attn_r = (const float*)d_in[3];
    const float* bias   = (const float*)d_in[4];
    const int*   src    = (const int*)d_in[5];
    const int*   dst    = (const int*)d_in[6];
    float* out = (float*)d_out;

    const int N = in_sizes[0] / D_IN;
    const int E = in_sizes[5];
    const int B = (N + 63) >> 6;    // dst-buckets of 64 nodes

    unsigned int* hbuf = (unsigned int*)d_ws;                       // N*64 u32 (f16 pairs)
    float* el        = (float*)(hbuf + (size_t)N * 64);             // N*4
    float* er        = el + (size_t)N * NHEAD;                      // N*4
    unsigned short* wf16 = (unsigned short*)(er + (size_t)N * NHEAD);  // 128*256 f16
    unsigned int* pairs = (unsigned int*)(wf16 + HD * D_IN);        // B*BCAP
    int*   srcs      = (int*)(pairs + (size_t)B * BCAP);            // B*BCAP
    int*   row_start = srcs + (size_t)B * BCAP;                     // N
    int*   degs      = row_start + N;                               // N
    int*   gcur      = degs + N;                                    // B

    const int GB  = (N + 31) / 32;       // gemm blocks (32-node tiles)
    const int ebl = (E + 4095) / 4096;   // bin blocks

    wconv_k<<<33, 256, 0, stream>>>(fcw, wf16, gcur, B);
    fused_k<<<GB + ebl, 256, 0, stream>>>(feat, wf16, attn_l, attn_r, hbuf, el, er,
                                          src, dst, gcur, pairs, N, E, B, GB);
    bucket_k<<<B, 256, 0, stream>>>(pairs, gcur, row_start, degs, srcs, N);
    agg_k<<<N, 64, 0, stream>>>(row_start, degs, srcs, el, er, hbuf, bias, out, N);
}

// Round 17
// 114.664 us; speedup vs baseline: 1.0837x; 1.0253x over previous
//
#include <hip/hip_runtime.h>
#include <hip/hip_bf16.h>
#include <math.h>

#define D_IN   256
#define HD     128
#define NHEAD  4
#define NEG_SLOPE 0.2f
#define CHUNK 32
#define MAXB  1024      // max dst-buckets (N <= 65536)
#define BCAP  2560      // padded edges per 64-dst bucket (mean 2048, +11 sigma)

typedef _Float16 h8 __attribute__((ext_vector_type(8)));
typedef _Float16 h4 __attribute__((ext_vector_type(4)));
typedef _Float16 h2 __attribute__((ext_vector_type(2)));
typedef float f4 __attribute__((ext_vector_type(4)));

// async global->LDS, 16 B/lane; LDS dest is wave-uniform base + lane*16 (HW-enforced)
__device__ __forceinline__ void gl2lds16(const void* g, void* l) {
    __builtin_amdgcn_global_load_lds(
        (const __attribute__((address_space(1))) void*)g,
        (__attribute__((address_space(3))) void*)l,
        16, 0, 0);
}

// ---------------- W f32 -> f16 (once) + zero gcur; 33 blocks ----------------
__global__ __launch_bounds__(256) void wconv_k(const float* __restrict__ fcw,
                                               unsigned short* __restrict__ wf16,
                                               int* __restrict__ gcur, int B) {
    const int t = threadIdx.x;
    if (blockIdx.x < 32) {
        int i = blockIdx.x * 256 + t;
        float4 v = *(const float4*)&fcw[i * 4];
        h4 p = {(_Float16)v.x, (_Float16)v.y, (_Float16)v.z, (_Float16)v.w};
        *(h4*)&wf16[i * 4] = p;
        return;
    }
    for (int i = t; i < B; i += 256) gcur[i] = 0;
}

// ---------------- fused: gemm blocks [0,GB) + bin blocks [GB,GB+ebl) ----------------
// gemm: 32-node tile; feat staged f32 via global_load_lds (pre-swizzled source),
// f32->f16 cvt folded into fragment reads. W preload in f16 (r14 proven).
__global__ __launch_bounds__(256) void fused_k(
        const float* __restrict__ feat, const unsigned short* __restrict__ wf16,
        const float* __restrict__ attn_l, const float* __restrict__ attn_r,
        unsigned int* __restrict__ hbuf, float* __restrict__ el, float* __restrict__ er,
        const int* __restrict__ src, const int* __restrict__ dst,
        int* __restrict__ gcur, unsigned int* __restrict__ pairs,
        int N, int E, int B, int GB) {
    __shared__ __align__(16) unsigned char smem[32 * 1024];   // 32 KB (union)
    const int t = threadIdx.x;

    if ((int)blockIdx.x >= GB) {
        // ================= bin body: key = dst bucket =================
        int* lcnt  = (int*)smem;          // 4 KB
        int* lbase = lcnt + MAXB;         // 4 KB
        for (int i = t; i < B; i += 256) lcnt[i] = 0;
        __syncthreads();
        const int base = ((int)blockIdx.x - GB) * 4096;
        int sv[16], dv[16];
        #pragma unroll
        for (int k = 0; k < 16; ++k) {
            int idx = base + k * 256 + t;
            if (idx < E) {
                sv[k] = src[idx];
                dv[k] = dst[idx];
                atomicAdd(&lcnt[dv[k] >> 6], 1);
            } else dv[k] = -1;
        }
        __syncthreads();
        for (int i = t; i < B; i += 256) {
            int c = lcnt[i];
            lbase[i] = c ? atomicAdd(&gcur[i], c) : 0;
            lcnt[i] = 0;
        }
        __syncthreads();
        #pragma unroll
        for (int k = 0; k < 16; ++k) {
            if (dv[k] >= 0) {
                int b = dv[k] >> 6;
                int r = lbase[b] + atomicAdd(&lcnt[b], 1);
                if (r < BCAP)
                    pairs[(size_t)b * BCAP + r] =
                        ((unsigned int)sv[k] << 6) | (unsigned int)(dv[k] & 63);
            }
        }
        return;
    }

    // ================= gemm body: 32 nodes x 128 out, K=256 =================
    unsigned char* lds_raw = smem;       // [32 rows][1024 B] f32, source-swizzled
    const int l  = t & 63;
    const int w  = t >> 6;          // wave index == head
    const int l4 = l >> 4;          // k-group 0..3
    const int lm = l & 15;
    const int n0 = blockIdx.x * 32;

    // B fragments: preload (overlaps feat staging; L2-resident)
    h8 breg[2][8];
    #pragma unroll
    for (int jt = 0; jt < 2; ++jt) {
        const unsigned short* wrow = wf16 + (size_t)(w * 32 + jt * 16 + lm) * D_IN;
        #pragma unroll
        for (int ks = 0; ks < 8; ++ks)
            breg[jt][ks] = *(const h8*)&wrow[ks * 32 + l4 * 8];
    }

    // stage feat tile [32][256] f32 -> LDS async; wave w stages rows w*8..w*8+7.
    // source pre-swizzled so that LDS[row*1024 + p] = src_row[p ^ ((row&7)<<4)].
    #pragma unroll
    for (int j = 0; j < 8; ++j) {
        const int row = w * 8 + j;
        if (n0 + row < N) {
            const char* g = (const char*)(feat + (size_t)(n0 + row) * D_IN)
                          + ((l * 16) ^ ((row & 7) << 4));
            gl2lds16(g, lds_raw + row * 1024);
        }
    }
    __syncthreads();

    f4 acc[2][2] = {};
    #pragma unroll
    for (int ks = 0; ks < 8; ++ks) {
        const int kb = ks * 128 + l4 * 32;   // byte offset of this lane's 8 f32 elems
        #pragma unroll
        for (int mt = 0; mt < 2; ++mt) {
            const int row = mt * 16 + lm;
            const int swz = (row & 7) << 4;
            f4 x0 = *(const f4*)(lds_raw + row * 1024 + (kb ^ swz));
            f4 x1 = *(const f4*)(lds_raw + row * 1024 + ((kb + 16) ^ swz));
            h8 af = {(_Float16)x0[0], (_Float16)x0[1], (_Float16)x0[2], (_Float16)x0[3],
                     (_Float16)x1[0], (_Float16)x1[1], (_Float16)x1[2], (_Float16)x1[3]};
            acc[mt][0] = __builtin_amdgcn_mfma_f32_16x16x32_f16(af, breg[0][ks], acc[mt][0], 0, 0, 0);
            acc[mt][1] = __builtin_amdgcn_mfma_f32_16x16x32_f16(af, breg[1][ks], acc[mt][1], 0, 0, 0);
        }
    }

    float al[2], ar[2];
    #pragma unroll
    for (int jt = 0; jt < 2; ++jt) {
        al[jt] = attn_l[w * 32 + jt * 16 + lm];
        ar[jt] = attn_r[w * 32 + jt * 16 + lm];
    }
    #pragma unroll
    for (int mt = 0; mt < 2; ++mt) {
        #pragma unroll
        for (int r = 0; r < 4; ++r) {
            float vl = acc[mt][0][r] * al[0] + acc[mt][1][r] * al[1];
            float vr = acc[mt][0][r] * ar[0] + acc[mt][1][r] * ar[1];
            #pragma unroll
            for (int o = 1; o < 16; o <<= 1) {
                vl += __shfl_xor(vl, o);
                vr += __shfl_xor(vr, o);
            }
            int node = n0 + mt * 16 + l4 * 4 + r;
            if (lm == 0 && node < N) {
                el[node * NHEAD + w] = vl;
                er[node * NHEAD + w] = vr;
            }
        }
    }

    // h -> LDS f16 [32][128] -> coalesced dump
    __syncthreads();
    unsigned short* hl = (unsigned short*)lds_raw;
    #pragma unroll
    for (int mt = 0; mt < 2; ++mt)
        #pragma unroll
        for (int jt = 0; jt < 2; ++jt)
            #pragma unroll
            for (int r = 0; r < 4; ++r) {
                int node_local = mt * 16 + l4 * 4 + r;
                int ch = w * 32 + jt * 16 + lm;
                _Float16 hf = (_Float16)acc[mt][jt][r];
                hl[node_local * 128 + ch] = __builtin_bit_cast(unsigned short, hf);
            }
    __syncthreads();
    const unsigned int* hu = (const unsigned int*)lds_raw;
    #pragma unroll
    for (int i = 0; i < 8; ++i) {
        int idx = t + 256 * i;
        int row = idx >> 6, c = idx & 63;
        if (n0 + row < N) hbuf[(size_t)(n0 + row) * 64 + c] = hu[row * 64 + c];
    }
}

// ---------------- per-bucket: sort into per-dst groups (uint4-vectorized scans) ----------------
__global__ __launch_bounds__(256) void bucket_k(const unsigned int* __restrict__ pairs,
                                                const int* __restrict__ gcur,
                                                int* __restrict__ row_start,
                                                int* __restrict__ degs,
                                                int* __restrict__ srcs, int N) {
    __shared__ int cnt64[64];
    __shared__ int base64[64];
    const int b = blockIdx.x;
    const int t = threadIdx.x;
    const int lo = b * BCAP;                 // BCAP % 4 == 0 -> 16B aligned
    const int len = min(gcur[b], BCAP);
    const int len4 = len & ~3;
    if (t < 64) cnt64[t] = 0;
    __syncthreads();
    for (int i = t * 4; i < len4; i += 1024) {
        uint4 p = *(const uint4*)&pairs[lo + i];
        atomicAdd(&cnt64[p.x & 63], 1);
        atomicAdd(&cnt64[p.y & 63], 1);
        atomicAdd(&cnt64[p.z & 63], 1);
        atomicAdd(&cnt64[p.w & 63], 1);
    }
    for (int i = len4 + t; i < len; i += 256)
        atomicAdd(&cnt64[pairs[lo + i] & 63], 1);
    __syncthreads();
    if (t < 64) {
        int v = cnt64[t];
        int x = v;
        #pragma unroll
        for (int o = 1; o < 64; o <<= 1) {
            int y = __shfl_up(x, o);
            if (t >= o) x += y;
        }
        int excl = lo + x - v;
        base64[t] = excl;
        int d = b * 64 + t;
        if (d < N) { row_start[d] = excl; degs[d] = v; }
        cnt64[t] = 0;
    }
    __syncthreads();
    for (int i = t * 4; i < len4; i += 1024) {
        uint4 p = *(const uint4*)&pairs[lo + i];
        int r0 = atomicAdd(&cnt64[p.x & 63], 1);
        srcs[base64[p.x & 63] + r0] = (int)(p.x >> 6);
        int r1 = atomicAdd(&cnt64[p.y & 63], 1);
        srcs[base64[p.y & 63] + r1] = (int)(p.y >> 6);
        int r2 = atomicAdd(&cnt64[p.z & 63], 1);
        srcs[base64[p.z & 63] + r2] = (int)(p.z >> 6);
        int r3 = atomicAdd(&cnt64[p.w & 63], 1);
        srcs[base64[p.w & 63] + r3] = (int)(p.w >> 6);
    }
    for (int i = len4 + t; i < len; i += 256) {
        unsigned int p = pairs[lo + i];
        int ld = p & 63;
        int r = atomicAdd(&cnt64[ld], 1);
        srcs[base64[ld] + r] = (int)(p >> 6);
    }
}

// ---------------- aggregate: one wave per dst, batched dwordx2 gather (r6/r12/r14 proven) ----------------
__global__ __launch_bounds__(64) void agg_k(
        const int* __restrict__ row_start, const int* __restrict__ degs,
        const int* __restrict__ srcs,
        const float* __restrict__ el, const float* __restrict__ er,
        const unsigned int* __restrict__ hbuf, const float* __restrict__ bias,
        float* __restrict__ out, int N) {
    __shared__ float exw[CHUNK * NHEAD];
    __shared__ int s_lds[CHUNK];
    const int d = blockIdx.x;
    const int l = threadIdx.x;
    const int he = l >> 4, es = l & 15;     // C1 roles: (head, edge-slot)
    const int half = l >> 5, cl = l & 31;   // C2 roles: (edge-half, channel-quad)
    const int hc = cl >> 3;                 // head of this lane's channels
    const int base = row_start[d];
    const int deg  = degs[d];
    const float erd = er[d * NHEAD + he];

    f4 acc = {0.f, 0.f, 0.f, 0.f};
    float den = 0.f;

    for (int c0 = 0; c0 < deg; c0 += CHUNK) {
        const int clen = min(CHUNK, deg - c0);
        __syncthreads();
        // C1: pre-issue both srcs loads, then both el loads, then exp
        int s0 = -1, s1 = -1;
        if (es < clen)      s0 = srcs[base + c0 + es];
        if (es + 16 < clen) s1 = srcs[base + c0 + es + 16];
        float e0 = 0.f, e1 = 0.f;
        if (s0 >= 0) e0 = el[s0 * NHEAD + he];
        if (s1 >= 0) e1 = el[s1 * NHEAD + he];
        if (s0 >= 0) {
            float v = e0 + erd;
            v = v > 0.f ? v : NEG_SLOPE * v;
            float ex = __expf(v);
            if (he == 0) s_lds[es] = s0;
            exw[es * NHEAD + he] = ex;
            den += ex;
        }
        if (s1 >= 0) {
            float v = e1 + erd;
            v = v > 0.f ? v : NEG_SLOPE * v;
            float ex = __expf(v);
            if (he == 0) s_lds[es + 16] = s1;
            exw[(es + 16) * NHEAD + he] = ex;
            den += ex;
        }
        __syncthreads();
        // C2: 8 edges per batch (4 pair-steps), loads issued before accumulation
        for (int jj = 0; jj < clen; jj += 8) {
            uint2 hv[4];
            float ex4[4];
            int e2v[4];
            #pragma unroll
            for (int k = 0; k < 4; ++k) {
                int e2 = jj + 2 * k + half;
                e2v[k] = (e2 < clen) ? e2 : -1;
                if (e2v[k] >= 0) {
                    int s = s_lds[e2];
                    hv[k] = *(const uint2*)&hbuf[(size_t)s * 64 + cl * 2];
                    ex4[k] = exw[e2 * NHEAD + hc];
                }
            }
            #pragma unroll
            for (int k = 0; k < 4; ++k) {
                if (e2v[k] >= 0) {
                    h2 p0 = __builtin_bit_cast(h2, hv[k].x);
                    h2 p1 = __builtin_bit_cast(h2, hv[k].y);
                    acc[0] += (float)p0[0] * ex4[k];
                    acc[1] += (float)p0[1] * ex4[k];
                    acc[2] += (float)p1[0] * ex4[k];
                    acc[3] += (float)p1[1] * ex4[k];
                }
            }
        }
    }

    // combine the two half-waves (same channels, alternating edges)
    #pragma unroll
    for (int k = 0; k < 4; ++k) acc[k] += __shfl_xor(acc[k], 32);
    // reduce den over the 16 lanes of each head group
    #pragma unroll
    for (int o = 1; o < 16; o <<= 1) den += __shfl_xor(den, o);
    float denc = __shfl(den, hc << 4);
    float r = 1.0f / fmaxf(denc, 1e-9f);

    if (half == 0) {
        float4 b4 = *(const float4*)&bias[cl * 4];
        float4 o4 = make_float4(acc[0] * r + b4.x, acc[1] * r + b4.y,
                                acc[2] * r + b4.z, acc[3] * r + b4.w);
        *(float4*)&out[(size_t)d * HD + cl * 4] = o4;
    }
}

extern "C" void kernel_launch(void* const* d_in, const int* in_sizes, int n_in,
                              void* d_out, int out_size, void* d_ws, size_t ws_size,
                              hipStream_t stream) {
    const float* feat   = (const float*)d_in[0];
    const float* fcw    = (const float*)d_in[1];
    const float* attn_l = (const float*)d_in[2];
    const float* attn_r = (const float*)d_in[3];
    const float* bias   = (const float*)d_in[4];
    const int*   src    = (const int*)d_in[5];
    const int*   dst    = (const int*)d_in[6];
    float* out = (float*)d_out;

    const int N = in_sizes[0] / D_IN;
    const int E = in_sizes[5];
    const int B = (N + 63) >> 6;    // dst-buckets of 64 nodes

    unsigned int* hbuf = (unsigned int*)d_ws;                       // N*64 u32 (f16 pairs)
    float* el        = (float*)(hbuf + (size_t)N * 64);             // N*4
    float* er        = el + (size_t)N * NHEAD;                      // N*4
    unsigned short* wf16 = (unsigned short*)(er + (size_t)N * NHEAD);  // 128*256 f16
    unsigned int* pairs = (unsigned int*)(wf16 + HD * D_IN);        // B*BCAP
    int*   srcs      = (int*)(pairs + (size_t)B * BCAP);            // B*BCAP
    int*   row_start = srcs + (size_t)B * BCAP;                     // N
    int*   degs      = row_start + N;                               // N
    int*   gcur      = degs + N;                                    // B

    const int GB  = (N + 31) / 32;       // gemm blocks (32-node tiles)
    const int ebl = (E + 4095) / 4096;   // bin blocks

    wconv_k<<<33, 256, 0, stream>>>(fcw, wf16, gcur, B);
    fused_k<<<GB + ebl, 256, 0, stream>>>(feat, wf16, attn_l, attn_r, hbuf, el, er,
                                          src, dst, gcur, pairs, N, E, B, GB);
    bucket_k<<<B, 256, 0, stream>>>(pairs, gcur, row_start, degs, srcs, N);
    agg_k<<<N, 64, 0, stream>>>(row_start, degs, srcs, el, er, hbuf, bias, out, N);
}